// Round 8
// baseline (28.318 us; speedup 1.0000x reference)
//
#include <hip/hip_runtime.h>
#include <math.h>

// 32 fixed taps from the problem definition (TAPS_INT), as exact fp32 values.
__device__ __constant__ float TAPS[32] = {
    -12.f,  -34.f,  -56.f,  -42.f,   18.f,  120.f,  260.f,  380.f,
    400.f,  290.f,   60.f, -210.f, -430.f, -500.f, -380.f, -120.f,
    180.f,  430.f,  540.f,  480.f,  280.f,   20.f, -220.f, -370.f,
   -400.f, -310.f, -150.f,   10.f,  120.f,  160.f,  130.f,   60.f
};

#define SCALE_INV (1.0f / 65536.0f)
#define NB  2048
#define NTH 256

typedef float floatx4 __attribute__((ext_vector_type(4)));

// Persistent grid-stride, 8 outputs/thread/chunk.
// Key change vs R7: all 10 window loads issue as ONE burst (explicit v[10]
// temporaries + sched_barrier(0) so the scheduler cannot sink loads into the
// FMA chain and shrink them to register-limited batches). One base address
// per chunk; the 10 loads use immediate offsets. Head chunks (c<4, outputs
// 0..31 == 0) take a separate zero-store path with no loads at all.
__global__ __launch_bounds__(NTH)
void fir32_burst(const float* __restrict__ x, float* __restrict__ y, int n) {
    const long nchunks = (long)n >> 3;             // 8 outputs per chunk
    const long stride = (long)NB * NTH;
    floatx4* y4 = reinterpret_cast<floatx4*>(y);

    for (long c = (long)blockIdx.x * NTH + threadIdx.x; c < nchunks; c += stride) {
        const long o4 = 2L * c;

        if (c < 4) {                               // outputs 0..31 defined as 0
            floatx4 z = {0.f, 0.f, 0.f, 0.f};
            __builtin_nontemporal_store(z, &y4[o4]);
            __builtin_nontemporal_store(z, &y4[o4 + 1]);
            continue;
        }

        // Window x[8c-32 .. 8c+7]: 10 aligned float4s from one base pointer.
        const floatx4* xw = reinterpret_cast<const floatx4*>(x + 8 * c - 32);
        floatx4 v[10];
        #pragma unroll
        for (int q = 0; q < 10; ++q) v[q] = xw[q]; // burst: imm offsets 0..144B
        __builtin_amdgcn_sched_barrier(0);         // keep all 10 in flight

        float w[40];
        #pragma unroll
        for (int q = 0; q < 10; ++q) {
            #pragma unroll
            for (int d = 0; d < 4; ++d) w[4 * q + d] = v[q][d];
        }

        float acc[8] = {0.f, 0.f, 0.f, 0.f, 0.f, 0.f, 0.f, 0.f};
        // Consume w in load-completion order: output j uses w[32+j-k], k=0..31.
        #pragma unroll
        for (int m = 0; m < 40; ++m) {
            #pragma unroll
            for (int j = 0; j < 8; ++j) {
                const int k = 32 + j - m;
                if (k >= 0 && k < 32)
                    acc[j] = fmaf(w[m], TAPS[k], acc[j]);
            }
        }

        floatx4 out0 = {floorf(acc[0] * SCALE_INV), floorf(acc[1] * SCALE_INV),
                        floorf(acc[2] * SCALE_INV), floorf(acc[3] * SCALE_INV)};
        floatx4 out1 = {floorf(acc[4] * SCALE_INV), floorf(acc[5] * SCALE_INV),
                        floorf(acc[6] * SCALE_INV), floorf(acc[7] * SCALE_INV)};
        __builtin_nontemporal_store(out0, &y4[o4]);
        __builtin_nontemporal_store(out1, &y4[o4 + 1]);
    }
}

extern "C" void kernel_launch(void* const* d_in, const int* in_sizes, int n_in,
                              void* d_out, int out_size, void* d_ws, size_t ws_size,
                              hipStream_t stream) {
    const float* x = (const float*)d_in[0];
    float* y = (float*)d_out;
    const int n = in_sizes[0];

    fir32_burst<<<dim3(NB), dim3(NTH), 0, stream>>>(x, y, n);
}